// Round 4
// baseline (402.986 us; speedup 1.0000x reference)
//
#include <hip/hip_runtime.h>

#define NTOK 4096          // B*N
#define TPB  16            // tokens per block
#define NBLK (NTOK / TPB)  // 256 blocks = 1 per CU
#define AST  264           // LDS A-tile row stride in shorts (bank-conflict pad)

using short8  = __attribute__((ext_vector_type(8))) short;
using floatx4 = __attribute__((ext_vector_type(4))) float;

static __device__ __forceinline__ float bf2f(short s) {
  union { unsigned u; float f; } v; v.u = ((unsigned)(unsigned short)s) << 16;
  return v.f;
}

// Packed f32x2 -> bf16x2 RNE conversion (single instr).
static __device__ __forceinline__ unsigned cvt_pk_bf16(float lo, float hi) {
  unsigned d;
  asm("v_cvt_pk_bf16_f32 %0, %1, %2" : "=v"(d) : "v"(lo), "v"(hi));
  return d;
}

// Branchless GELU via erf, Abramowitz-Stegun 7.1.25 (3-term, |eps|<=2.5e-5).
static __device__ __forceinline__ float fast_gelu(float z) {
  float x  = z * 0.70710678118654752f;
  float ax = fabsf(x);
  float t  = __builtin_amdgcn_rcpf(fmaf(0.47047f, ax, 1.0f));
  float em = __expf(-ax * ax);
  float p  = fmaf(fmaf(0.7478556f, t, -0.0958798f), t, 0.3480242f);
  float er = fmaf(-(p * t), em, 1.0f);               // erf(|x|) in [0,1)
  unsigned sgn = __float_as_uint(x) & 0x80000000u;
  er = __uint_as_float(__float_as_uint(er) | sgn);   // copysign
  return z * fmaf(0.5f, er, 0.5f);
}

// Coalesced pre-swizzle of W1[0:256,0:256] into bf16 B-fragment order:
// W1s[((s*16 + t)*64 + l)*8 + j] = bf16(W1[k*256 + n]),
//   k = s*32 + (l>>4)*8 + j, n = t*16 + (l&15).
__global__ void prep_w1(const float* __restrict__ W1, short* __restrict__ W1s) {
  const int n  = threadIdx.x;     // 0..255
  const int kb = blockIdx.x;      // 0..31
  const int s  = kb >> 2;
  const int l  = ((kb & 3) << 4) | (n & 15);
  const int t  = n >> 4;
  float f[8];
  #pragma unroll
  for (int j = 0; j < 8; ++j) f[j] = W1[(kb * 8 + j) * 256 + n];
  uint4 u;
  u.x = cvt_pk_bf16(f[0], f[1]);
  u.y = cvt_pk_bf16(f[2], f[3]);
  u.z = cvt_pk_bf16(f[4], f[5]);
  u.w = cvt_pk_bf16(f[6], f[7]);
  *(uint4*)(W1s + (((s * 16 + t) * 64 + l) << 3)) = u;
}

// Persistent-ish pipelined kernel: 256 blocks x 16 tokens. 512 thr / 8 waves,
// wave owns 32 output cols. __launch_bounds__(512,2) -> 256-reg cap: bfr[16]
// (64 VGPR, loaded ONCE per block) + v[8] float4 prefetch (32) + acc (32)
// all coexist without spill. Token t+1's global loads are issued right after
// barrier A of token t and land during t's GEMM/epilogue -> HBM streams
// continuously under compute instead of burst-then-idle.
__global__ void __launch_bounds__(512, 2) agg_kernel(
    const float* __restrict__ sampled, const float* __restrict__ valid,
    const float* __restrict__ y_norm, const float* __restrict__ W1,
    const float* __restrict__ b1, const float* __restrict__ W2,
    const float* __restrict__ b2, const short* __restrict__ W1s,
    float* __restrict__ out) {
  __shared__ __align__(16) short Abf[64 * AST];   // 33,792 B bf16 A tile
  __shared__ float wlog[8 * 64];                  // per-wave partial logits
  __shared__ float ynl[64];                       // y_norm
  __shared__ float ph[256];                       // phase-4 upper-half partials

  const int tid  = threadIdx.x;
  const int wv   = tid >> 6;       // wave 0..7 -> owns n in [32*wv, 32*wv+32)
  const int ln   = tid & 63;
  const int q    = ln >> 4;
  const int c15  = ln & 15;
  const int tok0 = blockIdx.x * TPB;

  if (tid < 64) ynl[tid] = y_norm[tid];

  // ---- prologue: issue token-0 A loads first (oldest in vmcnt FIFO) ----
  float4 v[8];
  {
    const float4* S4 = (const float4*)(sampled + ((size_t)tok0 << 14));
    #pragma unroll
    for (int it = 0; it < 8; ++it) v[it] = S4[it * 512 + tid];
  }
  float vnext = valid[tok0 * 64 + ln];

  // ---- per-block W1s slice: 16 x b128 -> registers, reused for all tokens ----
  short8 bfr[16];
  #pragma unroll
  for (int s = 0; s < 8; ++s)
    #pragma unroll
    for (int nt = 0; nt < 2; ++nt)
      bfr[s * 2 + nt] =
          *(const short8*)(W1s + (((s * 16 + wv * 2 + nt) * 64 + ln) << 3));

  float w2v[2], b1v[2], wlv[2];
  #pragma unroll
  for (int nt = 0; nt < 2; ++nt) {
    int n = wv * 32 + nt * 16 + c15;
    w2v[nt] = W2[n];
    b1v[nt] = b1[n];
    wlv[nt] = W1[65536 + n];        // W1[256][n] — the y-feature row
  }
  const float b2v = b2[0];

  float a0 = 0.f;                   // loop-carried lower-half phase-4 partial

  for (int t = 0; t < TPB; ++t) {
    // (C) guard Abf write-after-read vs prev token's phase 4; also makes
    // ph[] visible for the deferred store below.
    __syncthreads();
    if (t > 0 && tid < 256)
      out[(size_t)(tok0 + t - 1) * 256 + tid] = a0 + ph[tid];

    // ---- phase 0: convert v (token t) -> LDS bf16 tile ----
    {
      short* wp = Abf + wv * AST + (ln << 2);
      #pragma unroll
      for (int it = 0; it < 8; ++it) {
        uint2 dd;
        dd.x = cvt_pk_bf16(v[it].x, v[it].y);
        dd.y = cvt_pk_bf16(v[it].z, v[it].w);
        *(uint2*)(wp + it * 8 * AST) = dd;        // row y = it*8 + wv
      }
    }
    float vv = vnext;
    __syncthreads();                // (A) tile visible

    // ---- prefetch token t+1 (in flight during phases 1-4) ----
    if (t + 1 < TPB) {
      const float4* Sn = (const float4*)(sampled + ((size_t)(tok0 + t + 1) << 14));
      #pragma unroll
      for (int it = 0; it < 8; ++it) v[it] = Sn[it * 512 + tid];
      vnext = valid[(tok0 + t + 1) * 64 + ln];
    }

    // ---- phase 1: GEMM z[64x256] = A(bf16)*W1(bf16); B-frags in regs ----
    const floatx4 fzero = {0.f, 0.f, 0.f, 0.f};
    floatx4 acc[4][2];
    #pragma unroll
    for (int mt = 0; mt < 4; ++mt)
      #pragma unroll
      for (int nt = 0; nt < 2; ++nt) acc[mt][nt] = fzero;

    const short* ap = Abf + c15 * AST + q * 8;
    #pragma unroll
    for (int s = 0; s < 8; ++s) {
      short8 af[4];
      #pragma unroll
      for (int mt = 0; mt < 4; ++mt)
        af[mt] = *(const short8*)(ap + mt * 16 * AST + s * 32);
      #pragma unroll
      for (int nt = 0; nt < 2; ++nt)
        #pragma unroll
        for (int mt = 0; mt < 4; ++mt)
          acc[mt][nt] = __builtin_amdgcn_mfma_f32_16x16x32_bf16(
              af[mt], bfr[s * 2 + nt], acc[mt][nt], 0, 0, 0);
    }

    // ---- phase 2: h = gelu(z + y*W1_last + b1); partial logits = h.W2 ----
    #pragma unroll
    for (int mt = 0; mt < 4; ++mt) {
      #pragma unroll
      for (int r = 0; r < 4; ++r) {
        int m = mt * 16 + q * 4 + r;    // D row = quad*4 + reg
        float ym = ynl[m];
        float p = 0.f;
        #pragma unroll
        for (int nt = 0; nt < 2; ++nt) {
          float z = acc[mt][nt][r] + ym * wlv[nt] + b1v[nt];
          p += fast_gelu(z) * w2v[nt];
        }
        p += __shfl_xor(p, 1);
        p += __shfl_xor(p, 2);
        p += __shfl_xor(p, 4);
        p += __shfl_xor(p, 8);
        if (c15 == 0) wlog[wv * 64 + m] = p;
      }
    }
    __syncthreads();                // (B) wlog visible

    // ---- phase 3: masked softmax over Y=64, redundantly in every wave ----
    float lg = ((wlog[0 * 64 + ln] + wlog[1 * 64 + ln]) +
                (wlog[2 * 64 + ln] + wlog[3 * 64 + ln])) +
               ((wlog[4 * 64 + ln] + wlog[5 * 64 + ln]) +
                (wlog[6 * 64 + ln] + wlog[7 * 64 + ln])) + b2v;
    float lm = (vv < 0.5f) ? -10000.0f : lg;
    float mx = lm;
    #pragma unroll
    for (int d = 32; d > 0; d >>= 1) mx = fmaxf(mx, __shfl_xor(mx, d));
    float e  = __expf(lm - mx);
    float s1 = e;
    #pragma unroll
    for (int d = 32; d > 0; d >>= 1) s1 += __shfl_xor(s1, d);
    float wgt = e / s1 * vv;
    float s2  = wgt;
    #pragma unroll
    for (int d = 32; d > 0; d >>= 1) s2 += __shfl_xor(s2, d);
    wgt = wgt / fmaxf(s2, 1e-6f);   // lane ln holds weight for y=ln

    // ---- phase 4: out[c] = sum_y A_bf16[y][c]*w[y], y-split across halves.
    //      Store is deferred to next iteration top (after barrier C). ----
    if (tid < 256) {
      const short* Ac = Abf + tid;
      float p0 = 0.f, p1 = 0.f, p2 = 0.f, p3 = 0.f;
      #pragma unroll
      for (int y = 0; y < 32; y += 4) {
        p0 = fmaf(bf2f(Ac[(y + 0) * AST]), __shfl(wgt, y + 0), p0);
        p1 = fmaf(bf2f(Ac[(y + 1) * AST]), __shfl(wgt, y + 1), p1);
        p2 = fmaf(bf2f(Ac[(y + 2) * AST]), __shfl(wgt, y + 2), p2);
        p3 = fmaf(bf2f(Ac[(y + 3) * AST]), __shfl(wgt, y + 3), p3);
      }
      a0 = (p0 + p1) + (p2 + p3);
    } else {
      const short* Ac = Abf + (tid - 256);
      float p0 = 0.f, p1 = 0.f, p2 = 0.f, p3 = 0.f;
      #pragma unroll
      for (int y = 32; y < 64; y += 4) {
        p0 = fmaf(bf2f(Ac[(y + 0) * AST]), __shfl(wgt, y + 0), p0);
        p1 = fmaf(bf2f(Ac[(y + 1) * AST]), __shfl(wgt, y + 1), p1);
        p2 = fmaf(bf2f(Ac[(y + 2) * AST]), __shfl(wgt, y + 2), p2);
        p3 = fmaf(bf2f(Ac[(y + 3) * AST]), __shfl(wgt, y + 3), p3);
      }
      ph[tid - 256] = (p0 + p1) + (p2 + p3);
    }
  }

  // ---- epilogue: store the last token ----
  __syncthreads();
  if (tid < 256)
    out[(size_t)(tok0 + TPB - 1) * 256 + tid] = a0 + ph[tid];
}

extern "C" void kernel_launch(void* const* d_in, const int* in_sizes, int n_in,
                              void* d_out, int out_size, void* d_ws, size_t ws_size,
                              hipStream_t stream) {
  const float* sampled = (const float*)d_in[0];
  const float* valid   = (const float*)d_in[1];
  const float* y_norm  = (const float*)d_in[2];
  const float* W1      = (const float*)d_in[3];   // [257,256]
  const float* b1      = (const float*)d_in[4];
  const float* W2      = (const float*)d_in[5];
  const float* b2      = (const float*)d_in[6];
  short* W1s = (short*)d_ws;                      // 128 KiB swizzled bf16 W1
  float* out = (float*)d_out;

  prep_w1<<<32, 256, 0, stream>>>(W1, W1s);
  agg_kernel<<<NBLK, 512, 0, stream>>>(sampled, valid, y_norm, W1, b1, W2, b2, W1s, out);
}

// Round 5
// 387.324 us; speedup vs baseline: 1.0404x; 1.0404x over previous
//
#include <hip/hip_runtime.h>

#define NTOK 4096          // B*N
#define TPB  16            // tokens per block
#define NBLK (NTOK / TPB)  // 256 blocks = 1 per CU
#define AST  264           // LDS A-tile row stride in shorts (bank-conflict pad)

using short8  = __attribute__((ext_vector_type(8))) short;
using floatx4 = __attribute__((ext_vector_type(4))) float;

// Packed f32x2 -> bf16x2 RNE conversion (single instr).
static __device__ __forceinline__ unsigned cvt_pk_bf16(float lo, float hi) {
  unsigned d;
  asm("v_cvt_pk_bf16_f32 %0, %1, %2" : "=v"(d) : "v"(lo), "v"(hi));
  return d;
}

// Branchless GELU via erf, Abramowitz-Stegun 7.1.25 (3-term, |eps|<=2.5e-5).
static __device__ __forceinline__ float fast_gelu(float z) {
  float x  = z * 0.70710678118654752f;
  float ax = fabsf(x);
  float t  = __builtin_amdgcn_rcpf(fmaf(0.47047f, ax, 1.0f));
  float em = __expf(-ax * ax);
  float p  = fmaf(fmaf(0.7478556f, t, -0.0958798f), t, 0.3480242f);
  float er = fmaf(-(p * t), em, 1.0f);               // erf(|x|) in [0,1)
  unsigned sgn = __float_as_uint(x) & 0x80000000u;
  er = __uint_as_float(__float_as_uint(er) | sgn);   // copysign
  return z * fmaf(0.5f, er, 0.5f);
}

// Coalesced pre-swizzle of W1[0:256,0:256] into bf16 B-fragment order:
// W1s[((s*16 + t)*64 + l)*8 + j] = bf16(W1[k*256 + n]),
//   k = s*32 + (l>>4)*8 + j, n = t*16 + (l&15).
__global__ void prep_w1(const float* __restrict__ W1, short* __restrict__ W1s) {
  const int n  = threadIdx.x;     // 0..255
  const int kb = blockIdx.x;      // 0..31
  const int s  = kb >> 2;
  const int l  = ((kb & 3) << 4) | (n & 15);
  const int t  = n >> 4;
  float f[8];
  #pragma unroll
  for (int j = 0; j < 8; ++j) f[j] = W1[(kb * 8 + j) * 256 + n];
  uint4 u;
  u.x = cvt_pk_bf16(f[0], f[1]);
  u.y = cvt_pk_bf16(f[2], f[3]);
  u.z = cvt_pk_bf16(f[4], f[5]);
  u.w = cvt_pk_bf16(f[6], f[7]);
  *(uint4*)(W1s + (((s * 16 + t) * 64 + l) << 3)) = u;
}

// 256 blocks x 16 tokens, 512 thr / 8 waves, wave owns 32 output cols.
// vs r4: (1) phase 4 runs from the prefetch REGISTERS (thread tid holds
// A[8it+wv][4ln..4ln+3]) via wave-uniform readlane of wgt -> no LDS read
// chains, no bf2f; cross-wave combine through an 8KB pw exchange whose
// read is deferred past the next barrier A. (2) barriers per token: 3 -> 2
// (phase 4 no longer touches Abf; A separates ph3/4(t-1) from ph2(t) writes,
// B separates GEMM(t) reads from ph0(t+1) writes). (3) softmax drops the
// s1 reduction (cancels under renormalization) and b2 (shift-invariant):
// 6 fewer dependent cross-lane ops. v is double-buffered (vA/vB) with a
// 2x-unrolled macro so all indexing stays compile-time (no scratch).
__global__ void __launch_bounds__(512, 2) agg_kernel(
    const float* __restrict__ sampled, const float* __restrict__ valid,
    const float* __restrict__ y_norm, const float* __restrict__ W1,
    const float* __restrict__ b1, const float* __restrict__ W2,
    const float* __restrict__ b2, const short* __restrict__ W1s,
    float* __restrict__ out) {
  __shared__ __align__(16) short Abf[64 * AST];   // 33,792 B bf16 A tile
  __shared__ float wlog[8 * 64];                  // per-wave partial logits
  __shared__ float ynl[64];                       // y_norm
  __shared__ float pw[8 * 256];                   // phase-4 per-wave partials

  const int tid  = threadIdx.x;
  const int wv   = tid >> 6;       // wave 0..7 -> owns n in [32*wv, 32*wv+32)
  const int ln   = tid & 63;
  const int q    = ln >> 4;
  const int c15  = ln & 15;
  const int swv  = __builtin_amdgcn_readfirstlane(wv);   // SGPR wave id
  const int tok0 = blockIdx.x * TPB;

  if (tid < 64) ynl[tid] = y_norm[tid];

  // ---- prologue: token-0 A loads (thread holds rows y=8*it+wv, cols 4ln..) --
  float4 vA[8], vB[8];
  {
    const float4* S4 = (const float4*)(sampled + ((size_t)tok0 << 14));
    #pragma unroll
    for (int it = 0; it < 8; ++it) vA[it] = S4[it * 512 + tid];
  }
  float vvA = valid[tok0 * 64 + ln], vvB = 0.f;

  // ---- per-block W1s slice: 16 x b128 -> registers, reused all tokens ----
  short8 bfr[16];
  #pragma unroll
  for (int s = 0; s < 8; ++s)
    #pragma unroll
    for (int nt = 0; nt < 2; ++nt)
      bfr[s * 2 + nt] =
          *(const short8*)(W1s + (((s * 16 + wv * 2 + nt) * 64 + ln) << 3));

  float w2v[2], b1v[2], wlv[2];
  #pragma unroll
  for (int nt = 0; nt < 2; ++nt) {
    int n = wv * 32 + nt * 16 + c15;
    w2v[nt] = W2[n];
    b1v[nt] = b1[n];
    wlv[nt] = W1[65536 + n];        // W1[256][n] — the y-feature row
  }

#define TOKEN_ITER(VC, VN, VVC, VVN, T)                                        \
  {                                                                            \
    /* phase 0: convert VC -> LDS bf16 tile (row y = it*8+wv, shorts 4ln..) */ \
    {                                                                          \
      short* wp = Abf + wv * AST + (ln << 2);                                  \
      _Pragma("unroll")                                                        \
      for (int it = 0; it < 8; ++it) {                                         \
        uint2 dd;                                                              \
        dd.x = cvt_pk_bf16(VC[it].x, VC[it].y);                                \
        dd.y = cvt_pk_bf16(VC[it].z, VC[it].w);                                \
        *(uint2*)(wp + it * 8 * AST) = dd;                                     \
      }                                                                        \
    }                                                                          \
    __syncthreads(); /* (A) Abf + pw(T-1) visible */                           \
    /* prefetch token T+1 (in flight through GEMM/epilogue) */                 \
    if ((T) + 1 < TPB) {                                                       \
      const float4* Sn =                                                       \
          (const float4*)(sampled + ((size_t)(tok0 + (T) + 1) << 14));         \
      _Pragma("unroll")                                                        \
      for (int it = 0; it < 8; ++it) VN[it] = Sn[it * 512 + tid];              \
      VVN = valid[(tok0 + (T) + 1) * 64 + ln];                                 \
    }                                                                          \
    /* deferred combine+store of token T-1 from pw */                          \
    if ((T) > 0 && tid < 256) {                                                \
      float o = ((pw[0 * 256 + tid] + pw[1 * 256 + tid]) +                     \
                 (pw[2 * 256 + tid] + pw[3 * 256 + tid])) +                    \
                ((pw[4 * 256 + tid] + pw[5 * 256 + tid]) +                     \
                 (pw[6 * 256 + tid] + pw[7 * 256 + tid]));                     \
      out[(size_t)(tok0 + (T) - 1) * 256 + tid] = o;                           \
    }                                                                          \
    /* phase 1: GEMM z[64x256] = A(bf16)*W1(bf16); B-frags in regs */          \
    const floatx4 fzero = {0.f, 0.f, 0.f, 0.f};                                \
    floatx4 acc[4][2];                                                         \
    _Pragma("unroll")                                                          \
    for (int mt = 0; mt < 4; ++mt) {                                           \
      acc[mt][0] = fzero;                                                      \
      acc[mt][1] = fzero;                                                      \
    }                                                                          \
    const short* ap = Abf + c15 * AST + q * 8;                                 \
    _Pragma("unroll")                                                          \
    for (int s = 0; s < 8; ++s) {                                              \
      short8 af[4];                                                            \
      _Pragma("unroll")                                                        \
      for (int mt = 0; mt < 4; ++mt)                                           \
        af[mt] = *(const short8*)(ap + mt * 16 * AST + s * 32);                \
      _Pragma("unroll")                                                        \
      for (int nt = 0; nt < 2; ++nt)                                           \
        _Pragma("unroll")                                                      \
        for (int mt = 0; mt < 4; ++mt)                                         \
          acc[mt][nt] = __builtin_amdgcn_mfma_f32_16x16x32_bf16(               \
              af[mt], bfr[s * 2 + nt], acc[mt][nt], 0, 0, 0);                  \
    }                                                                          \
    /* phase 2: h = gelu(z + y*W1_last + b1); partial logits = h.W2 */         \
    _Pragma("unroll")                                                          \
    for (int mt = 0; mt < 4; ++mt) {                                           \
      _Pragma("unroll")                                                        \
      for (int r = 0; r < 4; ++r) {                                            \
        int m = mt * 16 + q * 4 + r;                                           \
        float ym = ynl[m];                                                     \
        float z0 = acc[mt][0][r] + ym * wlv[0] + b1v[0];                       \
        float z1 = acc[mt][1][r] + ym * wlv[1] + b1v[1];                       \
        float p = fast_gelu(z0) * w2v[0] + fast_gelu(z1) * w2v[1];             \
        p += __shfl_xor(p, 1);                                                 \
        p += __shfl_xor(p, 2);                                                 \
        p += __shfl_xor(p, 4);                                                 \
        p += __shfl_xor(p, 8);                                                 \
        if (c15 == 0) wlog[wv * 64 + m] = p;                                   \
      }                                                                        \
    }                                                                          \
    __syncthreads(); /* (B) wlog visible; Abf GEMM reads done */               \
    /* phase 3: masked softmax over Y=64 (s1 cancels; b2 shift-invariant) */   \
    float lg = ((wlog[0 * 64 + ln] + wlog[1 * 64 + ln]) +                      \
                (wlog[2 * 64 + ln] + wlog[3 * 64 + ln])) +                     \
               ((wlog[4 * 64 + ln] + wlog[5 * 64 + ln]) +                      \
                (wlog[6 * 64 + ln] + wlog[7 * 64 + ln]));                      \
    float lm = ((VVC) < 0.5f) ? -10000.0f : lg;                                \
    float mx = lm;                                                             \
    _Pragma("unroll")                                                          \
    for (int d = 32; d > 0; d >>= 1) mx = fmaxf(mx, __shfl_xor(mx, d));        \
    float e = __expf(lm - mx) * (VVC);                                         \
    float sd = e;                                                              \
    _Pragma("unroll")                                                          \
    for (int d = 32; d > 0; d >>= 1) sd += __shfl_xor(sd, d);                  \
    float wgt = e * __builtin_amdgcn_rcpf(fmaxf(sd, 1e-6f));                   \
    /* phase 4: per-wave partials from REGISTERS: thread holds */              \
    /* A[8it+wv][4ln..4ln+3] in VC; w[8it+wv] via wave-uniform readlane */     \
    float4 part = {0.f, 0.f, 0.f, 0.f};                                        \
    _Pragma("unroll")                                                          \
    for (int it = 0; it < 8; ++it) {                                           \
      float wy = __uint_as_float(__builtin_amdgcn_readlane(                    \
          (int)__float_as_uint(wgt), it * 8 + swv));                           \
      part.x = fmaf(VC[it].x, wy, part.x);                                     \
      part.y = fmaf(VC[it].y, wy, part.y);                                     \
      part.z = fmaf(VC[it].z, wy, part.z);                                     \
      part.w = fmaf(VC[it].w, wy, part.w);                                     \
    }                                                                          \
    *(float4*)(pw + wv * 256 + (ln << 2)) = part;                              \
  }

  for (int tt = 0; tt < TPB; tt += 2) {
    TOKEN_ITER(vA, vB, vvA, vvB, tt)
    TOKEN_ITER(vB, vA, vvB, vvA, tt + 1)
  }
#undef TOKEN_ITER

  // ---- epilogue: combine+store the last token ----
  __syncthreads();
  if (tid < 256) {
    float o = ((pw[0 * 256 + tid] + pw[1 * 256 + tid]) +
               (pw[2 * 256 + tid] + pw[3 * 256 + tid])) +
              ((pw[4 * 256 + tid] + pw[5 * 256 + tid]) +
               (pw[6 * 256 + tid] + pw[7 * 256 + tid]));
    out[(size_t)(tok0 + TPB - 1) * 256 + tid] = o;
  }
}

extern "C" void kernel_launch(void* const* d_in, const int* in_sizes, int n_in,
                              void* d_out, int out_size, void* d_ws, size_t ws_size,
                              hipStream_t stream) {
  const float* sampled = (const float*)d_in[0];
  const float* valid   = (const float*)d_in[1];
  const float* y_norm  = (const float*)d_in[2];
  const float* W1      = (const float*)d_in[3];   // [257,256]
  const float* b1      = (const float*)d_in[4];
  const float* W2      = (const float*)d_in[5];
  const float* b2      = (const float*)d_in[6];
  short* W1s = (short*)d_ws;                      // 128 KiB swizzled bf16 W1
  float* out = (float*)d_out;

  prep_w1<<<32, 256, 0, stream>>>(W1, W1s);
  agg_kernel<<<NBLK, 512, 0, stream>>>(sampled, valid, y_norm, W1, b1, W2, b2, W1s, out);
}